// Round 3
// baseline (1977.181 us; speedup 1.0000x reference)
//
#include <hip/hip_runtime.h>
#include <hip/hip_bf16.h>
#include <math.h>

// B=32, S=2048, D=128 causal attention.
// Inputs q,k,v FP32 (mask input ignored; causal by index).
// Outputs (a[B,S,S], out[B,S,D]) concatenated in d_out as FP32.

typedef __attribute__((ext_vector_type(8))) short bf16x8;   // 8 bf16 = 4 VGPRs
typedef __attribute__((ext_vector_type(4))) float f32x4;

#define MFMA(a, b, c) __builtin_amdgcn_mfma_f32_16x16x32_bf16((a), (b), (c), 0, 0, 0)

constexpr int   Sdim  = 2048;
constexpr int   Ddim  = 128;
constexpr int   BATCH = 32;
constexpr float INV_SCALE = 0.08838834764831845f;  // 1/sqrt(128)
constexpr float NEG_BIG   = -1e30f;
constexpr int   PADV = 8;   // vt row pad (bf16)
constexpr int   PADP = 8;   // pt row pad (bf16)
constexpr int   PADS = 4;   // ps row pad (fp32)

__device__ __forceinline__ bf16x8 pack8(const float* p) {
    float4 a = *(const float4*)p;
    float4 b = *(const float4*)(p + 4);
    union { __hip_bfloat16 h[8]; bf16x8 v; } u;
    u.h[0] = __float2bfloat16(a.x); u.h[1] = __float2bfloat16(a.y);
    u.h[2] = __float2bfloat16(a.z); u.h[3] = __float2bfloat16(a.w);
    u.h[4] = __float2bfloat16(b.x); u.h[5] = __float2bfloat16(b.y);
    u.h[6] = __float2bfloat16(b.z); u.h[7] = __float2bfloat16(b.w);
    return u.v;
}

__global__ __launch_bounds__(256, 2)
void attn_kernel(const float* __restrict__ qg,
                 const float* __restrict__ kg,
                 const float* __restrict__ vg,
                 float* __restrict__ a_out,
                 float* __restrict__ o_out)
{
    const int b    = blockIdx.y;
    const int qi   = blockIdx.x;        // q-tile (64 rows)
    const int tid  = threadIdx.x;
    const int wave = tid >> 6;          // each wave owns 16 q rows
    const int lane = tid & 63;
    const int li   = lane & 15;
    const int quad = lane >> 4;

    __shared__ __hip_bfloat16 vt[Ddim][64 + PADV];  // V^T tile: vt[d][key]
    __shared__ __hip_bfloat16 pt[64][64 + PADP];    // P (bf16) for PV A-frags
    __shared__ float          ps[64][64 + PADS];    // P (fp32) for coalesced a-store

    const size_t boff = (size_t)b * Sdim * Ddim;
    const float* qb = qg + boff;
    const float* kb = kg + boff;
    const float* vb = vg + boff;
    float* ab = a_out + (size_t)b * Sdim * Sdim;

    const int q0   = qi * 64;
    const int row0 = q0 + wave * 16;

    // ---- Q fragments (A-layout: A[m=li][k=quad*8+j]), kept in regs ----
    bf16x8 qf[4];
    {
        const float* qrow = qb + (size_t)(row0 + li) * Ddim + quad * 8;
        #pragma unroll
        for (int ks = 0; ks < 4; ++ks)
            qf[ks] = pack8(qrow + ks * 32);
    }

    // ---- zero-fill fully-masked columns: [64*(qi+1), S) for this wave's 16 rows ----
    {
        const int c0  = (qi + 1) * 64;
        const int zc4 = (Sdim - c0) >> 2;     // float4 chunks per row
        for (int rr = 0; rr < 16; ++rr) {
            float4* dst = (float4*)(ab + (size_t)(row0 + rr) * Sdim + c0);
            for (int c = lane; c < zc4; c += 64)
                dst[c] = make_float4(0.f, 0.f, 0.f, 0.f);
        }
    }

    // =================== Pass 1: row max m and denom l ===================
    float m[4], l[4];
    #pragma unroll
    for (int r = 0; r < 4; ++r) { m[r] = NEG_BIG; l[r] = 0.f; }

    for (int kt = 0; kt <= qi; ++kt) {
        const int kv0 = kt * 64;
        f32x4 acc[4];
        #pragma unroll
        for (int t = 0; t < 4; ++t) acc[t] = (f32x4){0.f, 0.f, 0.f, 0.f};

        const float* krow = kb + (size_t)(kv0 + li) * Ddim + quad * 8;
        #pragma unroll
        for (int t = 0; t < 4; ++t) {
            const float* kp = krow + (size_t)t * 16 * Ddim;
            #pragma unroll
            for (int ks = 0; ks < 4; ++ks) {
                bf16x8 kf = pack8(kp + ks * 32);
                acc[t] = MFMA(qf[ks], kf, acc[t]);
            }
        }

        float s[4][4];
        #pragma unroll
        for (int t = 0; t < 4; ++t)
            #pragma unroll
            for (int r = 0; r < 4; ++r) {
                float sv = acc[t][r] * INV_SCALE;
                if (kt == qi) {
                    int col = kv0 + t * 16 + li;
                    int row = row0 + quad * 4 + r;
                    if (col > row) sv = NEG_BIG;
                }
                s[t][r] = sv;
            }

        #pragma unroll
        for (int r = 0; r < 4; ++r) {
            float tm = fmaxf(fmaxf(s[0][r], s[1][r]), fmaxf(s[2][r], s[3][r]));
            #pragma unroll
            for (int off = 1; off < 16; off <<= 1)
                tm = fmaxf(tm, __shfl_xor(tm, off, 64));
            float mn    = fmaxf(m[r], tm);
            float alpha = __expf(m[r] - mn);   // 0 on first tile
            float se = __expf(s[0][r] - mn) + __expf(s[1][r] - mn)
                     + __expf(s[2][r] - mn) + __expf(s[3][r] - mn);
            #pragma unroll
            for (int off = 1; off < 16; off <<= 1)
                se += __shfl_xor(se, off, 64);
            l[r] = l[r] * alpha + se;
            m[r] = mn;
        }
    }

    float invl[4];
    #pragma unroll
    for (int r = 0; r < 4; ++r) invl[r] = 1.0f / l[r];

    // =================== Pass 2: write a, accumulate O ===================
    f32x4 oacc[8];
    #pragma unroll
    for (int n = 0; n < 8; ++n) oacc[n] = (f32x4){0.f, 0.f, 0.f, 0.f};

    for (int kt = 0; kt <= qi; ++kt) {
        const int kv0 = kt * 64;

        __syncthreads();  // vt/ps from previous iter fully consumed
        // stage V^T (bf16) into LDS: vt[d][key]
        #pragma unroll
        for (int it = 0; it < 8; ++it) {
            int c  = tid + it * 256;    // 0..2047 float4 chunks
            int kk = c >> 5;            // key row 0..63
            int d0 = (c & 31) * 4;      // dim col
            float4 vv = *(const float4*)(vb + (size_t)(kv0 + kk) * Ddim + d0);
            vt[d0 + 0][kk] = __float2bfloat16(vv.x);
            vt[d0 + 1][kk] = __float2bfloat16(vv.y);
            vt[d0 + 2][kk] = __float2bfloat16(vv.z);
            vt[d0 + 3][kk] = __float2bfloat16(vv.w);
        }
        __syncthreads();

        // recompute S tile
        f32x4 acc[4];
        #pragma unroll
        for (int t = 0; t < 4; ++t) acc[t] = (f32x4){0.f, 0.f, 0.f, 0.f};
        const float* krow = kb + (size_t)(kv0 + li) * Ddim + quad * 8;
        #pragma unroll
        for (int t = 0; t < 4; ++t) {
            const float* kp = krow + (size_t)t * 16 * Ddim;
            #pragma unroll
            for (int ks = 0; ks < 4; ++ks) {
                bf16x8 kf = pack8(kp + ks * 32);
                acc[t] = MFMA(qf[ks], kf, acc[t]);
            }
        }

        // p = exp(s-m)/l  ->  ps (fp32, for a-store) and pt (bf16, for PV)
        #pragma unroll
        for (int t = 0; t < 4; ++t)
            #pragma unroll
            for (int r = 0; r < 4; ++r) {
                float sv = acc[t][r] * INV_SCALE;
                int colL = t * 16 + li;
                int rowL = wave * 16 + quad * 4 + r;
                if (kt == qi && (kv0 + colL) > (q0 + rowL)) sv = NEG_BIG;
                float p = __expf(sv - m[r]) * invl[r];
                ps[rowL][colL] = p;
                pt[rowL][colL] = __float2bfloat16(p);
            }

        __syncthreads();  // ps complete across all waves

        // cooperative coalesced a-store: 64 rows x 64 cols fp32
        // 8 lanes cover 128 contiguous bytes per row
        #pragma unroll
        for (int it = 0; it < 2; ++it) {
            int rowL = (tid >> 3) + it * 32;
            float* dst = ab + (size_t)(q0 + rowL) * Sdim + kv0;
            #pragma unroll
            for (int j = 0; j < 2; ++j) {
                int c = (tid & 7) * 4 + j * 32;
                *(float4*)(dst + c) = *(const float4*)&ps[rowL][c];
            }
        }

        // PV: O[16][128] += P[16][64] @ V[64][128]
        #pragma unroll
        for (int ks = 0; ks < 2; ++ks) {
            bf16x8 pf = *(const bf16x8*)&pt[wave * 16 + li][ks * 32 + quad * 8];
            #pragma unroll
            for (int nt = 0; nt < 8; ++nt) {
                bf16x8 vf = *(const bf16x8*)&vt[nt * 16 + li][ks * 32 + quad * 8];
                oacc[nt] = MFMA(pf, vf, oacc[nt]);
            }
        }
    }

    // ---- write O (fp32) ----
    float* ob = o_out + ((size_t)b * Sdim + row0) * Ddim;
    #pragma unroll
    for (int nt = 0; nt < 8; ++nt)
        #pragma unroll
        for (int r = 0; r < 4; ++r)
            ob[(size_t)(quad * 4 + r) * Ddim + nt * 16 + li] = oacc[nt][r];
}

extern "C" void kernel_launch(void* const* d_in, const int* in_sizes, int n_in,
                              void* d_out, int out_size, void* d_ws, size_t ws_size,
                              hipStream_t stream)
{
    const float* q = (const float*)d_in[0];
    const float* k = (const float*)d_in[1];
    const float* v = (const float*)d_in[2];
    // d_in[3] = causal mask, ignored (reconstructed from indices)

    float* a = (float*)d_out;                             // [B,S,S]
    float* o = a + (size_t)BATCH * Sdim * Sdim;           // [B,S,D]

    dim3 grid(Sdim / 64, BATCH);
    attn_kernel<<<grid, 256, 0, stream>>>(q, k, v, a, o);
}